// Round 1
// baseline (424.972 us; speedup 1.0000x reference)
//
#include <hip/hip_runtime.h>

#define T_TOK 16
#define K_TOP 8
#define NEXP  64
#define DHID  2048
#define FINT  1024

#define NDQ    4                 // d-splits in up kernel
#define DQ_LEN (DHID / NDQ)      // 512
#define NFH    2                 // f-splits in down kernel
#define FH_LEN (FINT / NFH)      // 512
#define NDH    2                 // d-splits in down kernel
#define DH_LEN (DHID / NDH)      // 1024

// workspace layout (bytes)
#define ROUTE_OFF  0u
#define ACTIVE_OFF 4096u
#define HPART_OFF  8192u
#define HPART_SZ   ((size_t)NDQ * NEXP * FINT * T_TOK * 4)   // 16 MB
#define ABUF_OFF   (HPART_OFF + HPART_SZ)
#define ABUF_SZ    ((size_t)NEXP * FINT * T_TOK * 4)         // 4 MB
#define OPART_OFF  (ABUF_OFF + ABUF_SZ)                      // 16 MB follows

// ---------------------------------------------------------------------------
// K1: route[e][t] = sum_k w[t][k]*(idx[t][k]==e); active[e] flag.
// Deterministic (no atomics). Auto-detects whether the index buffer is
// int32 or int64 (reference declares int64; harness docs say int32).
// ---------------------------------------------------------------------------
__global__ void k_route(const int* __restrict__ idx, const float* __restrict__ w,
                        float* __restrict__ route, int* __restrict__ active) {
    __shared__ float r[NEXP * T_TOK];
    __shared__ int is64_s;
    const int tid = threadIdx.x;  // 256
    if (tid == 0) {
        // If data is little-endian int64, every odd int32 (high word) of the
        // first 64 entries is 0. For int32 layout those are random in [0,64).
        int allz = 1;
        for (int i = 1; i < 128; i += 2) allz &= (idx[i] == 0);
        is64_s = allz;
    }
    __syncthreads();
    const int is64 = is64_s;
    for (int i = tid; i < NEXP * T_TOK; i += 256) {
        const int e = i >> 4, t = i & 15;
        float s = 0.f;
#pragma unroll
        for (int k = 0; k < K_TOP; ++k) {
            const int flat = t * K_TOP + k;
            const int ev = is64 ? idx[2 * flat] : idx[flat];
            if (ev == e) s += w[flat];
        }
        r[i] = s;
        route[i] = s;
    }
    __syncthreads();
    if (tid < NEXP) {
        float s = 0.f;
        for (int t = 0; t < T_TOK; ++t) s += r[tid * T_TOK + t];
        active[tid] = (s != 0.f) ? 1 : 0;
    }
}

// ---------------------------------------------------------------------------
// K2: up-projection partials. Block = (expert e, d-quarter dq), 256 threads.
// h_part[dq][e][f][t] = sum_{d in dq} x[t][d] * Wu[e][d][f]
// ---------------------------------------------------------------------------
__global__ __launch_bounds__(256, 2) void k_up(
    const float* __restrict__ x, const float* __restrict__ Wu,
    const int* __restrict__ active, float* __restrict__ h_part) {
    const int e = blockIdx.x;
    const int dq = blockIdx.y;
    if (!active[e]) return;

    __shared__ float xT[DQ_LEN][20];  // padded stride: 16B-aligned rows, 8-way wr conflict
    const int tid = threadIdx.x;
    for (int t = 0; t < T_TOK; ++t) {
#pragma unroll
        for (int p = 0; p < DQ_LEN / 256; ++p) {  // 2 coalesced passes
            const int d = p * 256 + tid;
            xT[d][t] = x[t * DHID + dq * DQ_LEN + d];
        }
    }
    __syncthreads();

    const int f0 = (tid >> 6) * 256 + (tid & 63) * 4;  // wave covers 256 contiguous f
    const float* wup = Wu + ((size_t)e * DHID + (size_t)dq * DQ_LEN) * FINT + f0;

    float acc[T_TOK][4] = {};
#pragma unroll 4
    for (int d = 0; d < DQ_LEN; ++d) {
        const float4 wv = *reinterpret_cast<const float4*>(wup + (size_t)d * FINT);
#pragma unroll
        for (int t = 0; t < T_TOK; ++t) {
            const float xv = xT[d][t];
            acc[t][0] = fmaf(xv, wv.x, acc[t][0]);
            acc[t][1] = fmaf(xv, wv.y, acc[t][1]);
            acc[t][2] = fmaf(xv, wv.z, acc[t][2]);
            acc[t][3] = fmaf(xv, wv.w, acc[t][3]);
        }
    }

    float* hp = h_part + (((size_t)dq * NEXP + e) * FINT + f0) * T_TOK;
#pragma unroll
    for (int j = 0; j < 4; ++j)
#pragma unroll
        for (int t0 = 0; t0 < T_TOK; t0 += 4)
            *reinterpret_cast<float4*>(hp + (size_t)j * T_TOK + t0) =
                make_float4(acc[t0][j], acc[t0 + 1][j], acc[t0 + 2][j], acc[t0 + 3][j]);
}

// ---------------------------------------------------------------------------
// K3: a[e][f][t] = route[e][t] * relu(sum_dq h_part)^2
// ---------------------------------------------------------------------------
__global__ void k_act(const float* __restrict__ h_part, const float* __restrict__ route,
                      const int* __restrict__ active, float* __restrict__ a_buf) {
    const int e = blockIdx.y;
    if (!active[e]) return;
    const int i = blockIdx.x * 256 + threadIdx.x;  // [0, F*T/4)
    const int f = i >> 2, tq = i & 3;
    const size_t base = ((size_t)e * FINT + f) * T_TOK + tq * 4;

    float4 s = make_float4(0.f, 0.f, 0.f, 0.f);
#pragma unroll
    for (int dq = 0; dq < NDQ; ++dq) {
        const float4 h = *reinterpret_cast<const float4*>(
            h_part + (size_t)dq * ((size_t)NEXP * FINT * T_TOK) + base);
        s.x += h.x; s.y += h.y; s.z += h.z; s.w += h.w;
    }
    const float4 r4 = *reinterpret_cast<const float4*>(route + e * T_TOK + tq * 4);
    float4 o;
    float hx;
    hx = fmaxf(s.x, 0.f); o.x = r4.x * hx * hx;
    hx = fmaxf(s.y, 0.f); o.y = r4.y * hx * hx;
    hx = fmaxf(s.z, 0.f); o.z = r4.z * hx * hx;
    hx = fmaxf(s.w, 0.f); o.w = r4.w * hx * hx;
    *reinterpret_cast<float4*>(a_buf + base) = o;
}

// ---------------------------------------------------------------------------
// K4: down-projection partials. Block = (e, d-half dh, f-half fh), 256 threads.
// out_part[e][fh][t][d] = sum_{f in fh} a[e][f][t] * Wd[e][f][d]
// ---------------------------------------------------------------------------
__global__ __launch_bounds__(256, 2) void k_down(
    const float* __restrict__ a_buf, const float* __restrict__ Wd,
    const int* __restrict__ active, float* __restrict__ out_part) {
    const int e = blockIdx.x, dh = blockIdx.y, fh = blockIdx.z;
    if (!active[e]) return;

    __shared__ float aT[FH_LEN][T_TOK];  // 32 KB, same layout as a_buf chunk
    const int tid = threadIdx.x;
    const float* asrc = a_buf + ((size_t)e * FINT + (size_t)fh * FH_LEN) * T_TOK;
#pragma unroll
    for (int p = 0; p < (FH_LEN * T_TOK) / (256 * 4); ++p) {  // 8 float4 passes
        const int i4 = (p * 256 + tid) * 4;
        *reinterpret_cast<float4*>(&aT[0][0] + i4) =
            *reinterpret_cast<const float4*>(asrc + i4);
    }
    __syncthreads();

    const int d0 = dh * DH_LEN + tid * 4;
    const float* wd = Wd + ((size_t)e * FINT + (size_t)fh * FH_LEN) * DHID + d0;

    float acc[T_TOK][4] = {};
#pragma unroll 4
    for (int f = 0; f < FH_LEN; ++f) {
        const float4 wv = *reinterpret_cast<const float4*>(wd + (size_t)f * DHID);
#pragma unroll
        for (int t = 0; t < T_TOK; ++t) {
            const float av = aT[f][t];
            acc[t][0] = fmaf(av, wv.x, acc[t][0]);
            acc[t][1] = fmaf(av, wv.y, acc[t][1]);
            acc[t][2] = fmaf(av, wv.z, acc[t][2]);
            acc[t][3] = fmaf(av, wv.w, acc[t][3]);
        }
    }

    float* op = out_part + (((size_t)e * NFH + fh) * T_TOK) * DHID + d0;
#pragma unroll
    for (int t = 0; t < T_TOK; ++t)
        *reinterpret_cast<float4*>(op + (size_t)t * DHID) =
            make_float4(acc[t][0], acc[t][1], acc[t][2], acc[t][3]);
}

// ---------------------------------------------------------------------------
// K5: out[t][d] = sum over active e, fh of out_part[e][fh][t][d]
// Fully overwrites d_out (no zeroing needed).
// ---------------------------------------------------------------------------
__global__ void k_comb(const float* __restrict__ out_part, const int* __restrict__ active,
                       float* __restrict__ out) {
    const int i = blockIdx.x * 256 + threadIdx.x;  // [0, T*D/4)
    const int t = i >> 9;
    const int d = (i & 511) * 4;
    float4 s = make_float4(0.f, 0.f, 0.f, 0.f);
    for (int e = 0; e < NEXP; ++e) {
        if (!active[e]) continue;
#pragma unroll
        for (int fh = 0; fh < NFH; ++fh) {
            const float4 v = *reinterpret_cast<const float4*>(
                out_part + (((size_t)e * NFH + fh) * T_TOK + t) * DHID + d);
            s.x += v.x; s.y += v.y; s.z += v.z; s.w += v.w;
        }
    }
    *reinterpret_cast<float4*>(out + (size_t)t * DHID + d) = s;
}

// ---------------------------------------------------------------------------
extern "C" void kernel_launch(void* const* d_in, const int* in_sizes, int n_in,
                              void* d_out, int out_size, void* d_ws, size_t ws_size,
                              hipStream_t stream) {
    (void)in_sizes; (void)n_in; (void)out_size; (void)ws_size;
    const float* x   = (const float*)d_in[0];
    const int*   idx = (const int*)d_in[1];
    const float* w   = (const float*)d_in[2];
    const float* Wu  = (const float*)d_in[3];
    const float* Wd  = (const float*)d_in[4];
    float* out = (float*)d_out;

    char* ws = (char*)d_ws;
    float* route    = (float*)(ws + ROUTE_OFF);
    int*   active   = (int*)(ws + ACTIVE_OFF);
    float* h_part   = (float*)(ws + HPART_OFF);
    float* a_buf    = (float*)(ws + ABUF_OFF);
    float* out_part = (float*)(ws + OPART_OFF);

    k_route<<<1, 256, 0, stream>>>(idx, w, route, active);
    k_up<<<dim3(NEXP, NDQ), 256, 0, stream>>>(x, Wu, active, h_part);
    k_act<<<dim3((FINT * T_TOK / 4) / 256, NEXP), 256, 0, stream>>>(h_part, route, active, a_buf);
    k_down<<<dim3(NEXP, NDH, NFH), 256, 0, stream>>>(a_buf, Wd, active, out_part);
    k_comb<<<dim3((T_TOK * DHID / 4) / 256), 256, 0, stream>>>(out_part, active, out);
}

// Round 2
// 254.603 us; speedup vs baseline: 1.6692x; 1.6692x over previous
//
#include <hip/hip_runtime.h>

#define T_TOK 16
#define K_TOP 8
#define NEXP  64
#define DHID  2048
#define FINT  1024

// up kernel split: 8 d-chunks x 2 f-halves -> 1024 blocks
#define NDQ     8
#define DQ_LEN  (DHID / NDQ)      // 256
#define NFH_UP  2
#define FHU_LEN (FINT / NFH_UP)   // 512

// down kernel split: 4 d-halves x 4 f-quarters -> 1024 blocks
#define NDH    4
#define DH_LEN (DHID / NDH)       // 512
#define NFD    4
#define FD_LEN (FINT / NFD)       // 256

// workspace layout (bytes)
#define ROUTE_OFF  0u
#define ACTIVE_OFF 4096u
#define HPART_OFF  8192u
#define HPART_SZ   ((size_t)NDQ * NEXP * FINT * T_TOK * 4)   // 32 MB
#define ABUF_OFF   (HPART_OFF + HPART_SZ)
#define ABUF_SZ    ((size_t)NEXP * FINT * T_TOK * 4)         // 4 MB
#define OPART_OFF  (ABUF_OFF + ABUF_SZ)                      // 32 MB follows

// ---------------------------------------------------------------------------
// K1: route[e][t] = sum_k w[t][k]*(idx[t][k]==e); active[e] flag.
// Deterministic (no atomics). Auto-detects int32 vs int64 index layout.
// ---------------------------------------------------------------------------
__global__ void k_route(const int* __restrict__ idx, const float* __restrict__ w,
                        float* __restrict__ route, int* __restrict__ active) {
    __shared__ float r[NEXP * T_TOK];
    __shared__ int is64_s;
    const int tid = threadIdx.x;  // 256
    if (tid == 0) {
        int allz = 1;
        for (int i = 1; i < 128; i += 2) allz &= (idx[i] == 0);
        is64_s = allz;
    }
    __syncthreads();
    const int is64 = is64_s;
    for (int i = tid; i < NEXP * T_TOK; i += 256) {
        const int e = i >> 4, t = i & 15;
        float s = 0.f;
#pragma unroll
        for (int k = 0; k < K_TOP; ++k) {
            const int flat = t * K_TOP + k;
            const int ev = is64 ? idx[2 * flat] : idx[flat];
            if (ev == e) s += w[flat];
        }
        r[i] = s;
        route[i] = s;
    }
    __syncthreads();
    if (tid < NEXP) {
        float s = 0.f;
        for (int t = 0; t < T_TOK; ++t) s += r[tid * T_TOK + t];
        active[tid] = (s != 0.f) ? 1 : 0;
    }
}

// ---------------------------------------------------------------------------
// K2: up-projection partials. Block = (e, dq, fh), 256 threads, lane owns 2 f.
// h_part[dq][e][f][t] = sum_{d in dq} x[t][d] * Wu[e][d][f]
// ---------------------------------------------------------------------------
__global__ __launch_bounds__(256, 4) void k_up(
    const float* __restrict__ x, const float* __restrict__ Wu,
    const int* __restrict__ active, float* __restrict__ h_part) {
    const int e = blockIdx.x, dq = blockIdx.y, fh = blockIdx.z;
    if (!active[e]) return;

    __shared__ float xT[DQ_LEN][20];  // stride 20: b128-readable rows, spread banks
    const int tid = threadIdx.x;
    {
        const int d = tid;  // 256 threads cover 256 d
        const float* xp = x + dq * DQ_LEN + d;
#pragma unroll
        for (int t = 0; t < T_TOK; ++t) xT[d][t] = xp[t * DHID];
    }
    __syncthreads();

    const int f0 = fh * FHU_LEN + (tid >> 6) * 128 + (tid & 63) * 2;  // wave: 512B/row
    const float* wup = Wu + ((size_t)e * DHID + (size_t)dq * DQ_LEN) * FINT + f0;

    float acc[T_TOK][2] = {};
#pragma unroll 8
    for (int d = 0; d < DQ_LEN; ++d) {
        const float2 wv = *reinterpret_cast<const float2*>(wup + (size_t)d * FINT);
#pragma unroll
        for (int t = 0; t < T_TOK; ++t) {
            const float xv = xT[d][t];
            acc[t][0] = fmaf(xv, wv.x, acc[t][0]);
            acc[t][1] = fmaf(xv, wv.y, acc[t][1]);
        }
    }

    // lane's 2 f-columns are 2x64B contiguous in h_part (f stride = T_TOK)
    float* hp = h_part + (((size_t)dq * NEXP + e) * FINT + f0) * T_TOK;
#pragma unroll
    for (int j = 0; j < 2; ++j)
#pragma unroll
        for (int t0 = 0; t0 < T_TOK; t0 += 4)
            *reinterpret_cast<float4*>(hp + (size_t)j * T_TOK + t0) =
                make_float4(acc[t0][j], acc[t0 + 1][j], acc[t0 + 2][j], acc[t0 + 3][j]);
}

// ---------------------------------------------------------------------------
// K3: a[e][f][t] = route[e][t] * relu(sum_dq h_part)^2
// ---------------------------------------------------------------------------
__global__ void k_act(const float* __restrict__ h_part, const float* __restrict__ route,
                      const int* __restrict__ active, float* __restrict__ a_buf) {
    const int e = blockIdx.y;
    if (!active[e]) return;
    const int i = blockIdx.x * 256 + threadIdx.x;  // [0, F*T/4)
    const int f = i >> 2, tq = i & 3;
    const size_t base = ((size_t)e * FINT + f) * T_TOK + tq * 4;

    float4 s = make_float4(0.f, 0.f, 0.f, 0.f);
#pragma unroll
    for (int dq = 0; dq < NDQ; ++dq) {
        const float4 h = *reinterpret_cast<const float4*>(
            h_part + (size_t)dq * ((size_t)NEXP * FINT * T_TOK) + base);
        s.x += h.x; s.y += h.y; s.z += h.z; s.w += h.w;
    }
    const float4 r4 = *reinterpret_cast<const float4*>(route + e * T_TOK + tq * 4);
    float4 o;
    float hx;
    hx = fmaxf(s.x, 0.f); o.x = r4.x * hx * hx;
    hx = fmaxf(s.y, 0.f); o.y = r4.y * hx * hx;
    hx = fmaxf(s.z, 0.f); o.z = r4.z * hx * hx;
    hx = fmaxf(s.w, 0.f); o.w = r4.w * hx * hx;
    *reinterpret_cast<float4*>(a_buf + base) = o;
}

// ---------------------------------------------------------------------------
// K4: down-projection partials. Block = (e, dh, fq), 256 threads, lane owns 2 d.
// out_part[e][fq][t][d] = sum_{f in fq} a[e][f][t] * Wd[e][f][d]
// ---------------------------------------------------------------------------
__global__ __launch_bounds__(256, 4) void k_down(
    const float* __restrict__ a_buf, const float* __restrict__ Wd,
    const int* __restrict__ active, float* __restrict__ out_part) {
    const int e = blockIdx.x, dh = blockIdx.y, fq = blockIdx.z;
    if (!active[e]) return;

    __shared__ float aT[FD_LEN][T_TOK];  // 16 KB, linear copy of a chunk
    const int tid = threadIdx.x;
    const float* asrc = a_buf + ((size_t)e * FINT + (size_t)fq * FD_LEN) * T_TOK;
#pragma unroll
    for (int p = 0; p < (FD_LEN * T_TOK) / (256 * 4); ++p) {  // 4 float4 passes
        const int i4 = (p * 256 + tid) * 4;
        *reinterpret_cast<float4*>(&aT[0][0] + i4) =
            *reinterpret_cast<const float4*>(asrc + i4);
    }
    __syncthreads();

    const int d0 = dh * DH_LEN + (tid >> 6) * 128 + (tid & 63) * 2;  // wave: 512B/row
    const float* wd = Wd + ((size_t)e * FINT + (size_t)fq * FD_LEN) * DHID + d0;

    float acc[T_TOK][2] = {};
#pragma unroll 8
    for (int f = 0; f < FD_LEN; ++f) {
        const float2 wv = *reinterpret_cast<const float2*>(wd + (size_t)f * DHID);
#pragma unroll
        for (int t = 0; t < T_TOK; ++t) {
            const float av = aT[f][t];
            acc[t][0] = fmaf(av, wv.x, acc[t][0]);
            acc[t][1] = fmaf(av, wv.y, acc[t][1]);
        }
    }

    float* op = out_part + (((size_t)e * NFD + fq) * T_TOK) * DHID + d0;
#pragma unroll
    for (int t = 0; t < T_TOK; ++t)
        *reinterpret_cast<float2*>(op + (size_t)t * DHID) =
            make_float2(acc[t][0], acc[t][1]);
}

// ---------------------------------------------------------------------------
// K5: out[t][d] = sum over active e, fq of out_part[e][fq][t][d]
// Fully overwrites d_out (no zeroing needed).
// ---------------------------------------------------------------------------
__global__ void k_comb(const float* __restrict__ out_part, const int* __restrict__ active,
                       float* __restrict__ out) {
    const int i = blockIdx.x * 256 + threadIdx.x;  // [0, T*D/4)
    const int t = i >> 9;
    const int d = (i & 511) * 4;
    float4 s = make_float4(0.f, 0.f, 0.f, 0.f);
    for (int e = 0; e < NEXP; ++e) {
        if (!active[e]) continue;
#pragma unroll
        for (int fq = 0; fq < NFD; ++fq) {
            const float4 v = *reinterpret_cast<const float4*>(
                out_part + (((size_t)e * NFD + fq) * T_TOK + t) * DHID + d);
            s.x += v.x; s.y += v.y; s.z += v.z; s.w += v.w;
        }
    }
    *reinterpret_cast<float4*>(out + (size_t)t * DHID + d) = s;
}

// ---------------------------------------------------------------------------
extern "C" void kernel_launch(void* const* d_in, const int* in_sizes, int n_in,
                              void* d_out, int out_size, void* d_ws, size_t ws_size,
                              hipStream_t stream) {
    (void)in_sizes; (void)n_in; (void)out_size; (void)ws_size;
    const float* x   = (const float*)d_in[0];
    const int*   idx = (const int*)d_in[1];
    const float* w   = (const float*)d_in[2];
    const float* Wu  = (const float*)d_in[3];
    const float* Wd  = (const float*)d_in[4];
    float* out = (float*)d_out;

    char* ws = (char*)d_ws;
    float* route    = (float*)(ws + ROUTE_OFF);
    int*   active   = (int*)(ws + ACTIVE_OFF);
    float* h_part   = (float*)(ws + HPART_OFF);
    float* a_buf    = (float*)(ws + ABUF_OFF);
    float* out_part = (float*)(ws + OPART_OFF);

    k_route<<<1, 256, 0, stream>>>(idx, w, route, active);
    k_up<<<dim3(NEXP, NDQ, NFH_UP), 256, 0, stream>>>(x, Wu, active, h_part);
    k_act<<<dim3((FINT * T_TOK / 4) / 256, NEXP), 256, 0, stream>>>(h_part, route, active, a_buf);
    k_down<<<dim3(NEXP, NDH, NFD), 256, 0, stream>>>(a_buf, Wd, active, out_part);
    k_comb<<<dim3((T_TOK * DHID / 4) / 256), 256, 0, stream>>>(out_part, active, out);
}

// Round 3
// 230.890 us; speedup vs baseline: 1.8406x; 1.1027x over previous
//
#include <hip/hip_runtime.h>

#define T_TOK 16
#define K_TOP 8
#define NEXP  64
#define DHID  2048
#define FINT  1024

// up kernel: 16 d-chunks of 128; each block covers all 1024 f (4 waves x 256 f)
#define NDQ    16
#define DQ_LEN (DHID / NDQ)       // 128
// down kernel: 2 d-halves x 8 f-chunks of 128; block covers 1024 d (4 waves x 256 d)
#define NDH    2
#define NFD    8
#define FD_LEN (FINT / NFD)       // 128

// workspace layout (bytes)
#define ROUTE_OFF  0u
#define ACTIVE_OFF 4096u
#define HPART_OFF  8192u
#define HPART_SZ   ((size_t)NDQ * NEXP * FINT * T_TOK * 2)        // 32 MB bf16
#define ABUF_OFF   (HPART_OFF + HPART_SZ)
#define ABUF_SZ    ((size_t)NEXP * FINT * T_TOK * 4)              // 4 MB fp32
#define OPART_OFF  (ABUF_OFF + ABUF_SZ)
#define OPART_SZ   ((size_t)NEXP * NFD * T_TOK * DHID * 2)        // 32 MB bf16
#define COMB4_OFF  (OPART_OFF + OPART_SZ)                         // 512 KB fp32

typedef unsigned int  uint_t;
typedef unsigned short ushort_t;

__device__ __forceinline__ ushort_t f2bf(float f) {
    uint_t u = __builtin_bit_cast(uint_t, f);
    u += 0x7FFFu + ((u >> 16) & 1u);     // round-to-nearest-even
    return (ushort_t)(u >> 16);
}
__device__ __forceinline__ uint_t pk2(float lo, float hi) {
    return (uint_t)f2bf(lo) | ((uint_t)f2bf(hi) << 16);
}
__device__ __forceinline__ float bf_lo(uint_t v) {
    return __builtin_bit_cast(float, v << 16);
}
__device__ __forceinline__ float bf_hi(uint_t v) {
    return __builtin_bit_cast(float, v & 0xFFFF0000u);
}

// ---------------------------------------------------------------------------
// K1: route[e][t], active[e]. Deterministic; auto-detects int32 vs int64 idx.
// ---------------------------------------------------------------------------
__global__ void k_route(const int* __restrict__ idx, const float* __restrict__ w,
                        float* __restrict__ route, int* __restrict__ active) {
    __shared__ float r[NEXP * T_TOK];
    __shared__ int is64_s;
    const int tid = threadIdx.x;  // 256
    if (tid == 0) {
        int allz = 1;
        for (int i = 1; i < 128; i += 2) allz &= (idx[i] == 0);
        is64_s = allz;
    }
    __syncthreads();
    const int is64 = is64_s;
    for (int i = tid; i < NEXP * T_TOK; i += 256) {
        const int e = i >> 4, t = i & 15;
        float s = 0.f;
#pragma unroll
        for (int k = 0; k < K_TOP; ++k) {
            const int flat = t * K_TOP + k;
            const int ev = is64 ? idx[2 * flat] : idx[flat];
            if (ev == e) s += w[flat];
        }
        r[i] = s;
        route[i] = s;
    }
    __syncthreads();
    if (tid < NEXP) {
        float s = 0.f;
        for (int t = 0; t < T_TOK; ++t) s += r[tid * T_TOK + t];
        active[tid] = (s != 0.f) ? 1 : 0;
    }
}

// 16 FMAs feeding 4 j-accumulator arrays from one weight float4 + one x scalar
#define FMA_T(t, xs)                                   \
    acc0[t] = fmaf((xs), w4.x, acc0[t]);               \
    acc1[t] = fmaf((xs), w4.y, acc1[t]);               \
    acc2[t] = fmaf((xs), w4.z, acc2[t]);               \
    acc3[t] = fmaf((xs), w4.w, acc3[t]);

// ---------------------------------------------------------------------------
// K2: up-projection. Block=(e,dq), 4 waves x 256 f, lane owns 4 f (float4).
// h_part[dq][e][f][t] (bf16) = sum_{d in dq} x[t][d] * Wu[e][d][f]
// ---------------------------------------------------------------------------
__global__ __launch_bounds__(256, 4) void k_up(
    const float* __restrict__ x, const float* __restrict__ Wu,
    const int* __restrict__ active, ushort_t* __restrict__ h_part) {
    const int e = blockIdx.x, dq = blockIdx.y;
    if (!active[e]) return;

    __shared__ float xT[DQ_LEN][T_TOK];  // broadcast reads -> no conflicts
    const int tid = threadIdx.x;
    {
        const int d = tid & 127;
        const int th = tid >> 7;
        const float* xp = x + dq * DQ_LEN + d;
#pragma unroll
        for (int t = 0; t < T_TOK / 2; ++t) xT[d][2 * t + th] = xp[(2 * t + th) * DHID];
    }
    __syncthreads();

    const int f0 = (tid >> 6) * 256 + (tid & 63) * 4;
    const float* wup = Wu + ((size_t)e * DHID + (size_t)dq * DQ_LEN) * FINT + f0;

    float acc0[T_TOK] = {}, acc1[T_TOK] = {}, acc2[T_TOK] = {}, acc3[T_TOK] = {};
#pragma unroll 4
    for (int d = 0; d < DQ_LEN; ++d) {
        const float4 w4 = *reinterpret_cast<const float4*>(wup + (size_t)d * FINT);
        const float4 xa = *reinterpret_cast<const float4*>(&xT[d][0]);
        const float4 xb = *reinterpret_cast<const float4*>(&xT[d][4]);
        const float4 xc = *reinterpret_cast<const float4*>(&xT[d][8]);
        const float4 xd = *reinterpret_cast<const float4*>(&xT[d][12]);
        FMA_T(0, xa.x)  FMA_T(1, xa.y)  FMA_T(2, xa.z)  FMA_T(3, xa.w)
        FMA_T(4, xb.x)  FMA_T(5, xb.y)  FMA_T(6, xb.z)  FMA_T(7, xb.w)
        FMA_T(8, xc.x)  FMA_T(9, xc.y)  FMA_T(10, xc.z) FMA_T(11, xc.w)
        FMA_T(12, xd.x) FMA_T(13, xd.y) FMA_T(14, xd.z) FMA_T(15, xd.w)
    }

    // lane's 4 f-columns: each 16 bf16 = 32 B contiguous
    ushort_t* hp = h_part + (((size_t)dq * NEXP + e) * FINT + f0) * T_TOK;
#define STORE_COL(A, jj)                                                        \
    {                                                                           \
        uint4 u0, u1;                                                           \
        u0.x = pk2(A[0], A[1]);   u0.y = pk2(A[2], A[3]);                       \
        u0.z = pk2(A[4], A[5]);   u0.w = pk2(A[6], A[7]);                       \
        u1.x = pk2(A[8], A[9]);   u1.y = pk2(A[10], A[11]);                     \
        u1.z = pk2(A[12], A[13]); u1.w = pk2(A[14], A[15]);                     \
        *reinterpret_cast<uint4*>(hp + (jj) * T_TOK) = u0;                      \
        *reinterpret_cast<uint4*>(hp + (jj) * T_TOK + 8) = u1;                  \
    }
    STORE_COL(acc0, 0) STORE_COL(acc1, 1) STORE_COL(acc2, 2) STORE_COL(acc3, 3)
#undef STORE_COL
}

// ---------------------------------------------------------------------------
// K3: a[e][f][t] (fp32) = route[e][t] * relu(sum_dq h_part)^2
// thread handles 8 contiguous bf16 (half an f-column)
// ---------------------------------------------------------------------------
__global__ void k_act(const ushort_t* __restrict__ h_part, const float* __restrict__ route,
                      const int* __restrict__ active, float* __restrict__ a_buf) {
    const int e = blockIdx.y;
    if (!active[e]) return;
    const int i = blockIdx.x * 256 + threadIdx.x;        // [0, F*T/8) = 2048
    const size_t base = (size_t)e * (FINT * T_TOK) + (size_t)i * 8;

    float s[8] = {};
#pragma unroll
    for (int dq = 0; dq < NDQ; ++dq) {
        const uint4 hv = *reinterpret_cast<const uint4*>(
            h_part + (size_t)dq * ((size_t)NEXP * FINT * T_TOK) + base);
        s[0] += bf_lo(hv.x); s[1] += bf_hi(hv.x);
        s[2] += bf_lo(hv.y); s[3] += bf_hi(hv.y);
        s[4] += bf_lo(hv.z); s[5] += bf_hi(hv.z);
        s[6] += bf_lo(hv.w); s[7] += bf_hi(hv.w);
    }
    const int t0 = (i & 1) * 8;
    const float* r = route + e * T_TOK + t0;
    float o[8];
#pragma unroll
    for (int k = 0; k < 8; ++k) {
        const float h = fmaxf(s[k], 0.f);
        o[k] = r[k] * h * h;
    }
    *reinterpret_cast<float4*>(a_buf + base) = make_float4(o[0], o[1], o[2], o[3]);
    *reinterpret_cast<float4*>(a_buf + base + 4) = make_float4(o[4], o[5], o[6], o[7]);
}

// ---------------------------------------------------------------------------
// K4: down-projection. Block=(e,dh,fq), 4 waves x 256 d, lane owns 4 d.
// out_part[e][fq][t][d] (bf16) = sum_{f in fq} a[e][f][t] * Wd[e][f][d]
// ---------------------------------------------------------------------------
__global__ __launch_bounds__(256, 4) void k_down(
    const float* __restrict__ a_buf, const float* __restrict__ Wd,
    const int* __restrict__ active, ushort_t* __restrict__ out_part) {
    const int e = blockIdx.x, dh = blockIdx.y, fq = blockIdx.z;
    if (!active[e]) return;

    __shared__ float aT[FD_LEN][T_TOK];  // 8 KB, linear copy
    const int tid = threadIdx.x;
    const float* asrc = a_buf + ((size_t)e * FINT + (size_t)fq * FD_LEN) * T_TOK;
#pragma unroll
    for (int p = 0; p < 2; ++p) {
        const int i4 = (p * 256 + tid) * 4;
        *reinterpret_cast<float4*>(&aT[0][0] + i4) =
            *reinterpret_cast<const float4*>(asrc + i4);
    }
    __syncthreads();

    const int d0 = dh * 1024 + (tid >> 6) * 256 + (tid & 63) * 4;
    const float* wd = Wd + ((size_t)e * FINT + (size_t)fq * FD_LEN) * DHID + d0;

    float acc0[T_TOK] = {}, acc1[T_TOK] = {}, acc2[T_TOK] = {}, acc3[T_TOK] = {};
#pragma unroll 4
    for (int f = 0; f < FD_LEN; ++f) {
        const float4 w4 = *reinterpret_cast<const float4*>(wd + (size_t)f * DHID);
        const float4 xa = *reinterpret_cast<const float4*>(&aT[f][0]);
        const float4 xb = *reinterpret_cast<const float4*>(&aT[f][4]);
        const float4 xc = *reinterpret_cast<const float4*>(&aT[f][8]);
        const float4 xd = *reinterpret_cast<const float4*>(&aT[f][12]);
        FMA_T(0, xa.x)  FMA_T(1, xa.y)  FMA_T(2, xa.z)  FMA_T(3, xa.w)
        FMA_T(4, xb.x)  FMA_T(5, xb.y)  FMA_T(6, xb.z)  FMA_T(7, xb.w)
        FMA_T(8, xc.x)  FMA_T(9, xc.y)  FMA_T(10, xc.z) FMA_T(11, xc.w)
        FMA_T(12, xd.x) FMA_T(13, xd.y) FMA_T(14, xd.z) FMA_T(15, xd.w)
    }

    // out_part[e][fq][t][d0..d0+3]: per t, 4 bf16 = 8 B; wave row = 512 B contiguous
    ushort_t* op = out_part + (((size_t)e * NFD + fq) * T_TOK) * DHID + d0;
#pragma unroll
    for (int t = 0; t < T_TOK; ++t) {
        uint2 u;
        u.x = pk2(acc0[t], acc1[t]);
        u.y = pk2(acc2[t], acc3[t]);
        *reinterpret_cast<uint2*>(op + (size_t)t * DHID) = u;
    }
}

// ---------------------------------------------------------------------------
// K5a: comb4[eq][t][d] = sum over 16 experts (x8 fq) of out_part  (256 blocks)
// ---------------------------------------------------------------------------
__global__ void k_comb1(const ushort_t* __restrict__ out_part, const int* __restrict__ active,
                        float* __restrict__ comb4) {
    const int eq = blockIdx.y;                       // 0..3
    const int i = blockIdx.x * 256 + threadIdx.x;    // [0, T*D/2)
    const int t = i >> 10;
    const int dp = (i & 1023) * 2;
    const size_t off = (size_t)t * DHID + dp;

    float s0 = 0.f, s1 = 0.f;
    for (int e = eq * 16; e < eq * 16 + 16; ++e) {
        if (!active[e]) continue;
#pragma unroll
        for (int fq = 0; fq < NFD; ++fq) {
            const uint_t v = *reinterpret_cast<const uint_t*>(
                out_part + ((size_t)(e * NFD + fq) * T_TOK) * DHID + off);
            s0 += bf_lo(v);
            s1 += bf_hi(v);
        }
    }
    *reinterpret_cast<float2*>(comb4 + (size_t)eq * T_TOK * DHID + off) =
        make_float2(s0, s1);
}

// ---------------------------------------------------------------------------
// K5b: out[t][d] = sum_eq comb4[eq][t][d]   (fully overwrites d_out)
// ---------------------------------------------------------------------------
__global__ void k_comb2(const float* __restrict__ comb4, float* __restrict__ out) {
    const int i = blockIdx.x * 256 + threadIdx.x;    // [0, T*D/4)
    const size_t off = (size_t)i * 4;
    float4 s = make_float4(0.f, 0.f, 0.f, 0.f);
#pragma unroll
    for (int q = 0; q < 4; ++q) {
        const float4 v = *reinterpret_cast<const float4*>(
            comb4 + (size_t)q * T_TOK * DHID + off);
        s.x += v.x; s.y += v.y; s.z += v.z; s.w += v.w;
    }
    *reinterpret_cast<float4*>(out + off) = s;
}

// ---------------------------------------------------------------------------
extern "C" void kernel_launch(void* const* d_in, const int* in_sizes, int n_in,
                              void* d_out, int out_size, void* d_ws, size_t ws_size,
                              hipStream_t stream) {
    (void)in_sizes; (void)n_in; (void)out_size; (void)ws_size;
    const float* x   = (const float*)d_in[0];
    const int*   idx = (const int*)d_in[1];
    const float* w   = (const float*)d_in[2];
    const float* Wu  = (const float*)d_in[3];
    const float* Wd  = (const float*)d_in[4];
    float* out = (float*)d_out;

    char* ws = (char*)d_ws;
    float*    route    = (float*)(ws + ROUTE_OFF);
    int*      active   = (int*)(ws + ACTIVE_OFF);
    ushort_t* h_part   = (ushort_t*)(ws + HPART_OFF);
    float*    a_buf    = (float*)(ws + ABUF_OFF);
    ushort_t* out_part = (ushort_t*)(ws + OPART_OFF);
    float*    comb4    = (float*)(ws + COMB4_OFF);

    k_route<<<1, 256, 0, stream>>>(idx, w, route, active);
    k_up<<<dim3(NEXP, NDQ), 256, 0, stream>>>(x, Wu, active, h_part);
    k_act<<<dim3((FINT * T_TOK / 8) / 256, NEXP), 256, 0, stream>>>(h_part, route, active, a_buf);
    k_down<<<dim3(NEXP, NDH, NFD), 256, 0, stream>>>(a_buf, Wd, active, out_part);
    k_comb1<<<dim3((T_TOK * DHID / 2) / 256, 4), 256, 0, stream>>>(out_part, active, comb4);
    k_comb2<<<dim3((T_TOK * DHID / 4) / 256), 256, 0, stream>>>(comb4, out);
}

// Round 4
// 214.929 us; speedup vs baseline: 1.9773x; 1.0743x over previous
//
#include <hip/hip_runtime.h>

#define T_TOK 16
#define K_TOP 8
#define NEXP  64
#define DHID  2048
#define FINT  1024

// workspace layout (bytes)
#define ROUTE_OFF 0u                              // 64*16 fp32 = 4 KB
#define AIDX_OFF  4096u                           // 64 int
#define NA_OFF    (AIDX_OFF + 256u)               // 1 int
#define XT_OFF    8192u                           // 2048*16 fp32 = 128 KB
#define ABUF_OFF  (XT_OFF + 131072u)              // 64*1024*16 fp32 = 4 MB
#define OPART_OFF (ABUF_OFF + 4194304u)           // 64*16*2048 fp32 = 8 MB

// ---------------------------------------------------------------------------
// K1: route[e][t]; compacted active-expert list aidx[0..nA). Deterministic.
// Auto-detects int32 vs int64 index layout.
// ---------------------------------------------------------------------------
__global__ void k_route(const int* __restrict__ idx, const float* __restrict__ w,
                        float* __restrict__ route, int* __restrict__ aidx,
                        int* __restrict__ nA) {
    __shared__ float r[NEXP * T_TOK];
    __shared__ int is64_s;
    const int tid = threadIdx.x;  // 256
    if (tid == 0) {
        int allz = 1;
        for (int i = 1; i < 128; i += 2) allz &= (idx[i] == 0);
        is64_s = allz;
    }
    __syncthreads();
    const int is64 = is64_s;
    for (int i = tid; i < NEXP * T_TOK; i += 256) {
        const int e = i >> 4, t = i & 15;
        float s = 0.f;
#pragma unroll
        for (int k = 0; k < K_TOP; ++k) {
            const int flat = t * K_TOP + k;
            const int ev = is64 ? idx[2 * flat] : idx[flat];
            if (ev == e) s += w[flat];
        }
        r[i] = s;
        route[i] = s;
    }
    __syncthreads();
    if (tid == 0) {
        int n = 0;
        for (int e = 0; e < NEXP; ++e) {
            float s = 0.f;
            for (int t = 0; t < T_TOK; ++t) s += r[e * T_TOK + t];
            if (s != 0.f) aidx[n++] = e;
        }
        *nA = n;
    }
}

// ---------------------------------------------------------------------------
// K2: transpose x [T][D] -> xT [D][T] (128 KB) so LDS staging is linear.
// ---------------------------------------------------------------------------
__global__ void k_xpose(const float* __restrict__ x, float* __restrict__ xT) {
    const int tid = threadIdx.x;              // 256
    const int d = blockIdx.x * 64 + (tid & 63);
    const int tq = tid >> 6;                  // 0..3
    float4 v;
    v.x = x[(tq * 4 + 0) * DHID + d];
    v.y = x[(tq * 4 + 1) * DHID + d];
    v.z = x[(tq * 4 + 2) * DHID + d];
    v.w = x[(tq * 4 + 3) * DHID + d];
    *reinterpret_cast<float4*>(xT + d * T_TOK + tq * 4) = v;
}

// 16 FMAs feeding 4 accumulator arrays from one weight float4 + one scalar
#define FMA_T(t, xs)                                   \
    acc0[t] = fmaf((xs), w4.x, acc0[t]);               \
    acc1[t] = fmaf((xs), w4.y, acc1[t]);               \
    acc2[t] = fmaf((xs), w4.z, acc2[t]);               \
    acc3[t] = fmaf((xs), w4.w, acc3[t]);

#define FMA_BLOCK()                                                       \
    {                                                                     \
        const float4 xa = *reinterpret_cast<const float4*>(&lds[base]);   \
        const float4 xb = *reinterpret_cast<const float4*>(&lds[base+4]); \
        const float4 xc = *reinterpret_cast<const float4*>(&lds[base+8]); \
        const float4 xd = *reinterpret_cast<const float4*>(&lds[base+12]);\
        FMA_T(0, xa.x)  FMA_T(1, xa.y)  FMA_T(2, xa.z)  FMA_T(3, xa.w)   \
        FMA_T(4, xb.x)  FMA_T(5, xb.y)  FMA_T(6, xb.z)  FMA_T(7, xb.w)   \
        FMA_T(8, xc.x)  FMA_T(9, xc.y)  FMA_T(10, xc.z) FMA_T(11, xc.w)  \
        FMA_T(12, xd.x) FMA_T(13, xd.y) FMA_T(14, xd.z) FMA_T(15, xd.w)  \
    }

// cross-wave reduction region: region*4096 + (j*16+t)*64 + lane  (conflict-free)
#define RED_WRITE(reg)                                                   \
    {                                                                    \
        float* p = lds + (reg) * 4096 + lane;                            \
        _Pragma("unroll") for (int t = 0; t < 16; ++t) {                 \
            p[(0 * 16 + t) * 64] = acc0[t];                              \
            p[(1 * 16 + t) * 64] = acc1[t];                              \
            p[(2 * 16 + t) * 64] = acc2[t];                              \
            p[(3 * 16 + t) * 64] = acc3[t];                              \
        }                                                                \
    }
#define RED_READ(reg)                                                    \
    {                                                                    \
        const float* p = lds + (reg) * 4096 + lane;                      \
        _Pragma("unroll") for (int t = 0; t < 16; ++t) {                 \
            acc0[t] += p[(0 * 16 + t) * 64];                             \
            acc1[t] += p[(1 * 16 + t) * 64];                             \
            acc2[t] += p[(2 * 16 + t) * 64];                             \
            acc3[t] += p[(3 * 16 + t) * 64];                             \
        }                                                                \
    }

// ---------------------------------------------------------------------------
// K3: fused up-proj + relu^2 + route. Block=(active expert, f-quarter),
// 1024 threads = 16 waves; wave w owns d-chunk [w*128, +128); lane owns 4 f.
// Cross-wave d-reduction via LDS tree; wave 0 applies act and writes a_buf.
// a_buf[e][f][t] = route[e][t] * relu(sum_d x[t][d]*Wu[e][d][f])^2
// ---------------------------------------------------------------------------
__global__ __launch_bounds__(1024, 4) void k_up(
    const float* __restrict__ xT, const float* __restrict__ Wu,
    const float* __restrict__ route, const int* __restrict__ aidx,
    const int* __restrict__ nAp, float* __restrict__ a_buf) {
    const int b = blockIdx.x;
    if (b >= 4 * (*nAp)) return;
    const int e = aidx[b >> 2];
    const int fq = b & 3;
    const int tid = threadIdx.x;
    const int wid = tid >> 6, lane = tid & 63;

    __shared__ float lds[16384];  // 64 KB: x half-tile, then reduction scratch

    float acc0[T_TOK] = {}, acc1[T_TOK] = {}, acc2[T_TOK] = {}, acc3[T_TOK] = {};

    const float* wcol = Wu + (size_t)e * DHID * FINT + fq * 256 + lane * 4;

#pragma unroll
    for (int ph = 0; ph < 2; ++ph) {
        if (ph) __syncthreads();  // all waves done reading previous half
        // stage xT rows [ph*1024, +1024) linearly (conflict-free, coalesced)
        {
            const float4* src = reinterpret_cast<const float4*>(xT + ph * 1024 * T_TOK);
            float4* dst = reinterpret_cast<float4*>(lds);
#pragma unroll
            for (int i = 0; i < 4; ++i) dst[i * 1024 + tid] = src[i * 1024 + tid];
        }
        __syncthreads();
        const float* wp = wcol + (size_t)(ph * 1024 + wid * 64) * FINT;
#pragma unroll 2
        for (int dd = 0; dd < 64; ++dd) {
            const float4 w4 = *reinterpret_cast<const float4*>(wp + (size_t)dd * FINT);
            const int base = (wid * 64 + dd) * T_TOK;
            FMA_BLOCK()
        }
    }

    // reduction: 16 waves -> wave 0 (rounds use <=4 regions of 16 KB)
    __syncthreads();
    if (wid >= 8 && wid < 12) RED_WRITE(wid - 8)
    __syncthreads();
    if (wid < 4) RED_READ(wid)
    __syncthreads();
    if (wid >= 12) RED_WRITE(wid - 12)
    __syncthreads();
    if (wid >= 4 && wid < 8) RED_READ(wid - 4)
    __syncthreads();
    if (wid >= 4 && wid < 8) RED_WRITE(wid - 4)
    __syncthreads();
    if (wid < 4) RED_READ(wid)
    __syncthreads();
    if (wid == 2 || wid == 3) RED_WRITE(wid - 2)
    __syncthreads();
    if (wid < 2) RED_READ(wid)
    __syncthreads();
    if (wid == 1) RED_WRITE(0)
    __syncthreads();

    if (wid == 0) {
        RED_READ(0)
        float rt[T_TOK];
#pragma unroll
        for (int t = 0; t < T_TOK; ++t) rt[t] = route[e * T_TOK + t];
        float* ap = a_buf + ((size_t)e * FINT + fq * 256 + lane * 4) * T_TOK;
#define ACT1(A, t) (rt[t] * fmaxf(A[t], 0.f) * fmaxf(A[t], 0.f))
#define STORE_COL(A, jj)                                                              \
    *reinterpret_cast<float4*>(ap + (jj) * T_TOK + 0) =                               \
        make_float4(ACT1(A, 0), ACT1(A, 1), ACT1(A, 2), ACT1(A, 3));                  \
    *reinterpret_cast<float4*>(ap + (jj) * T_TOK + 4) =                               \
        make_float4(ACT1(A, 4), ACT1(A, 5), ACT1(A, 6), ACT1(A, 7));                  \
    *reinterpret_cast<float4*>(ap + (jj) * T_TOK + 8) =                               \
        make_float4(ACT1(A, 8), ACT1(A, 9), ACT1(A, 10), ACT1(A, 11));                \
    *reinterpret_cast<float4*>(ap + (jj) * T_TOK + 12) =                              \
        make_float4(ACT1(A, 12), ACT1(A, 13), ACT1(A, 14), ACT1(A, 15));
        STORE_COL(acc0, 0) STORE_COL(acc1, 1) STORE_COL(acc2, 2) STORE_COL(acc3, 3)
#undef STORE_COL
#undef ACT1
    }
}

// ---------------------------------------------------------------------------
// K4: down-proj. Block=(active expert, d-chunk of 512), 1024 threads.
// wave (wd = wid>>3, wf = wid&7): d in [dc*512 + wd*256, +256) (lane owns 4 d),
// f in [wf*128, +128). Cross-wave f-reduction via LDS per wd-group.
// out_part[e][t][d] = sum_f a[e][f][t] * Wd[e][f][d]
// ---------------------------------------------------------------------------
__global__ __launch_bounds__(1024, 4) void k_down(
    const float* __restrict__ a_buf, const float* __restrict__ Wd,
    const int* __restrict__ aidx, const int* __restrict__ nAp,
    float* __restrict__ out_part) {
    const int b = blockIdx.x;
    if (b >= 4 * (*nAp)) return;
    const int e = aidx[b >> 2];
    const int dc = b & 3;
    const int tid = threadIdx.x;
    const int wid = tid >> 6, lane = tid & 63;
    const int wd = wid >> 3, wf = wid & 7;

    __shared__ float lds[16384];  // 64 KB: a[e] stage, then reduction scratch

    // stage a[e] (1024 f x 16 t fp32 = 64 KB) linearly
    {
        const float4* src = reinterpret_cast<const float4*>(a_buf + (size_t)e * FINT * T_TOK);
        float4* dst = reinterpret_cast<float4*>(lds);
#pragma unroll
        for (int i = 0; i < 4; ++i) dst[i * 1024 + tid] = src[i * 1024 + tid];
    }
    __syncthreads();

    const int d0 = dc * 512 + wd * 256 + lane * 4;
    const float* wp = Wd + ((size_t)e * FINT + wf * 128) * DHID + d0;

    float acc0[T_TOK] = {}, acc1[T_TOK] = {}, acc2[T_TOK] = {}, acc3[T_TOK] = {};
#pragma unroll 2
    for (int ff = 0; ff < 128; ++ff) {
        const float4 w4 = *reinterpret_cast<const float4*>(wp + (size_t)ff * DHID);
        const int base = (wf * 128 + ff) * T_TOK;
        FMA_BLOCK()
    }

    // reduction: 8 wf-waves -> wf 0, per wd-group
    __syncthreads();
    if (wd == 0 && wf >= 4) RED_WRITE(wf - 4)
    __syncthreads();
    if (wd == 0 && wf < 4) RED_READ(wf)
    __syncthreads();
    if (wd == 1 && wf >= 4) RED_WRITE(wf - 4)
    __syncthreads();
    if (wd == 1 && wf < 4) RED_READ(wf)
    __syncthreads();
    if (wf == 2 || wf == 3) RED_WRITE(wd * 2 + wf - 2)
    __syncthreads();
    if (wf < 2) RED_READ(wd * 2 + wf)
    __syncthreads();
    if (wf == 1) RED_WRITE(wd)
    __syncthreads();

    if (wf == 0) {
        RED_READ(wd)
        float* op = out_part + (size_t)e * (T_TOK * DHID) + d0;
#pragma unroll
        for (int t = 0; t < T_TOK; ++t)
            *reinterpret_cast<float4*>(op + (size_t)t * DHID) =
                make_float4(acc0[t], acc1[t], acc2[t], acc3[t]);
    }
}

// ---------------------------------------------------------------------------
// K5: out[t][d] = sum over active e of out_part[e][t][d]. Overwrites d_out.
// ---------------------------------------------------------------------------
__global__ void k_comb(const float* __restrict__ out_part, const int* __restrict__ aidx,
                       const int* __restrict__ nAp, float* __restrict__ out) {
    const int i = blockIdx.x * 256 + threadIdx.x;  // [0, T*D/4)
    const int nA = *nAp;
    const size_t off = (size_t)i * 4;
    float4 s = make_float4(0.f, 0.f, 0.f, 0.f);
    for (int a = 0; a < nA; ++a) {
        const float4 v = *reinterpret_cast<const float4*>(
            out_part + (size_t)aidx[a] * (T_TOK * DHID) + off);
        s.x += v.x; s.y += v.y; s.z += v.z; s.w += v.w;
    }
    *reinterpret_cast<float4*>(out + off) = s;
}

// ---------------------------------------------------------------------------
extern "C" void kernel_launch(void* const* d_in, const int* in_sizes, int n_in,
                              void* d_out, int out_size, void* d_ws, size_t ws_size,
                              hipStream_t stream) {
    (void)in_sizes; (void)n_in; (void)out_size; (void)ws_size;
    const float* x   = (const float*)d_in[0];
    const int*   idx = (const int*)d_in[1];
    const float* w   = (const float*)d_in[2];
    const float* Wu  = (const float*)d_in[3];
    const float* Wd  = (const float*)d_in[4];
    float* out = (float*)d_out;

    char* ws = (char*)d_ws;
    float* route    = (float*)(ws + ROUTE_OFF);
    int*   aidx     = (int*)(ws + AIDX_OFF);
    int*   nA       = (int*)(ws + NA_OFF);
    float* xT       = (float*)(ws + XT_OFF);
    float* a_buf    = (float*)(ws + ABUF_OFF);
    float* out_part = (float*)(ws + OPART_OFF);

    k_route<<<1, 256, 0, stream>>>(idx, w, route, aidx, nA);
    k_xpose<<<DHID / 64, 256, 0, stream>>>(x, xT);
    k_up<<<4 * NEXP, 1024, 0, stream>>>(xT, Wu, route, aidx, nA, a_buf);
    k_down<<<4 * NEXP, 1024, 0, stream>>>(a_buf, Wd, aidx, nA, out_part);
    k_comb<<<(T_TOK * DHID / 4) / 256, 256, 0, stream>>>(out_part, aidx, nA, out);
}

// Round 5
// 196.999 us; speedup vs baseline: 2.1572x; 1.0910x over previous
//
#include <hip/hip_runtime.h>

#define T_TOK 16
#define K_TOP 8
#define NEXP  64
#define DHID  2048
#define FINT  1024

typedef unsigned int   uint_t;
typedef unsigned short ushort_t;
typedef float f32x4 __attribute__((ext_vector_type(4)));

// workspace layout (bytes)
#define ROUTE_OFF 0u
#define AIDX_OFF  4096u
#define NA_OFF    (AIDX_OFF + 256u)
#define XT_OFF    8192u                          // 2048*16 fp32 = 128 KB
#define ABUF_OFF  (XT_OFF + 131072u)             // 64*1024*16 bf16 = 2 MB
#define OPART_OFF (ABUF_OFF + 2097152u)          // 64*16*2048 fp32 = 8 MB

__device__ __forceinline__ ushort_t f2bf(float f) {
    uint_t u = __builtin_bit_cast(uint_t, f);
    u += 0x7FFFu + ((u >> 16) & 1u);   // RNE
    return (ushort_t)(u >> 16);
}
__device__ __forceinline__ uint_t pk2(float lo, float hi) {
    return (uint_t)f2bf(lo) | ((uint_t)f2bf(hi) << 16);
}
__device__ __forceinline__ float bf_lo(uint_t v) { return __builtin_bit_cast(float, v << 16); }
__device__ __forceinline__ float bf_hi(uint_t v) { return __builtin_bit_cast(float, v & 0xFFFF0000u); }

// ---------------------------------------------------------------------------
// K1: x transpose [T][D]->[D][T] (all 32 blocks) + route/aidx/nA (block 0).
// ---------------------------------------------------------------------------
__global__ void k_prep(const float* __restrict__ x, const int* __restrict__ idx,
                       const float* __restrict__ w, float* __restrict__ xT,
                       float* __restrict__ route, int* __restrict__ aidx,
                       int* __restrict__ nA) {
    const int tid = threadIdx.x;                 // 256
    const int d = blockIdx.x * 64 + (tid & 63);
    const int tq = tid >> 6;
    float4 v;
    v.x = x[(tq * 4 + 0) * DHID + d];
    v.y = x[(tq * 4 + 1) * DHID + d];
    v.z = x[(tq * 4 + 2) * DHID + d];
    v.w = x[(tq * 4 + 3) * DHID + d];
    *reinterpret_cast<float4*>(xT + d * T_TOK + tq * 4) = v;

    if (blockIdx.x != 0) return;
    __shared__ float r[NEXP * T_TOK];
    __shared__ int is64_s;
    if (tid == 0) {
        int allz = 1;
        for (int i = 1; i < 128; i += 2) allz &= (idx[i] == 0);
        is64_s = allz;
    }
    __syncthreads();
    const int is64 = is64_s;
    for (int i = tid; i < NEXP * T_TOK; i += 256) {
        const int e = i >> 4, t = i & 15;
        float s = 0.f;
#pragma unroll
        for (int k = 0; k < K_TOP; ++k) {
            const int flat = t * K_TOP + k;
            const int ev = is64 ? idx[2 * flat] : idx[flat];
            if (ev == e) s += w[flat];
        }
        r[i] = s;
        route[i] = s;
    }
    __syncthreads();
    if (tid == 0) {
        int n = 0;
        for (int e = 0; e < NEXP; ++e) {
            float s = 0.f;
            for (int t = 0; t < T_TOK; ++t) s += r[e * T_TOK + t];
            if (s != 0.f) aidx[n++] = e;
        }
        *nA = n;
    }
}

// ---- shared inner-loop machinery (both streaming kernels) ------------------
#define FMA4(t, xs)                              \
    acc0[t] = fmaf((xs), w4.x, acc0[t]);         \
    acc1[t] = fmaf((xs), w4.y, acc1[t]);         \
    acc2[t] = fmaf((xs), w4.z, acc2[t]);         \
    acc3[t] = fmaf((xs), w4.w, acc3[t]);
#define FMA_PAIR(u, t0_)                                        \
    { const float xl = bf_lo(u), xh = bf_hi(u);                 \
      FMA4(t0_, xl) FMA4((t0_) + 1, xh) }
#define STEP(jj, B)                                                         \
    { const uint4 q0 = xqw[(jj) * 2]; const uint4 q1 = xqw[(jj) * 2 + 1];   \
      const f32x4 w4 = (B);                                                 \
      FMA_PAIR(q0.x, 0) FMA_PAIR(q0.y, 2) FMA_PAIR(q0.z, 4) FMA_PAIR(q0.w, 6) \
      FMA_PAIR(q1.x, 8) FMA_PAIR(q1.y, 10) FMA_PAIR(q1.z, 12) FMA_PAIR(q1.w, 14) }
#define LDW(j) __builtin_nontemporal_load(wrow + (size_t)(j) * WSTEP)

// bf16 reduction region = 2048 uints (8 KB): layout [j(4)][tp(8)][lane(64)]
#define RW(reg)                                                         \
    { uint_t* p = lds_u + (reg) * 2048 + lane;                          \
      _Pragma("unroll") for (int tp = 0; tp < 8; ++tp) {                \
          p[(0 * 8 + tp) * 64] = pk2(acc0[2 * tp], acc0[2 * tp + 1]);   \
          p[(1 * 8 + tp) * 64] = pk2(acc1[2 * tp], acc1[2 * tp + 1]);   \
          p[(2 * 8 + tp) * 64] = pk2(acc2[2 * tp], acc2[2 * tp + 1]);   \
          p[(3 * 8 + tp) * 64] = pk2(acc3[2 * tp], acc3[2 * tp + 1]); } }
#define RR(reg)                                                         \
    { const uint_t* p = lds_u + (reg) * 2048 + lane;                    \
      _Pragma("unroll") for (int tp = 0; tp < 8; ++tp) {                \
          uint_t u;                                                     \
          u = p[(0 * 8 + tp) * 64]; acc0[2 * tp] += bf_lo(u); acc0[2 * tp + 1] += bf_hi(u); \
          u = p[(1 * 8 + tp) * 64]; acc1[2 * tp] += bf_lo(u); acc1[2 * tp + 1] += bf_hi(u); \
          u = p[(2 * 8 + tp) * 64]; acc2[2 * tp] += bf_lo(u); acc2[2 * tp + 1] += bf_hi(u); \
          u = p[(3 * 8 + tp) * 64]; acc3[2 * tp] += bf_lo(u); acc3[2 * tp + 1] += bf_hi(u); } }

// ---------------------------------------------------------------------------
// K2: fused up-proj + relu^2 + route. Block=(active e, f-quarter of 256).
// 16 waves; wave owns 128 d-rows; lane owns 4 f. x staged bf16 (64 KB), one
// barrier; depth-4 rotating weight prefetch; bf16 tree reduction 16->1.
// ---------------------------------------------------------------------------
__global__ __launch_bounds__(1024, 4) void k_up(
    const float* __restrict__ xT, const float* __restrict__ Wu,
    const float* __restrict__ route, const int* __restrict__ aidx,
    const int* __restrict__ nAp, ushort_t* __restrict__ a_buf) {
    const int b = blockIdx.x;
    if (b >= 4 * (*nAp)) return;
    const int e = aidx[b >> 2];
    const int fq = b & 3;
    const int tid = threadIdx.x;
    const int wid = tid >> 6, lane = tid & 63;

    __shared__ __align__(16) uint_t lds_u[16384];  // 64 KB

    {   // stage xT fp32 -> bf16 packed [d][tp]; linear, coalesced
        const float4* src = reinterpret_cast<const float4*>(xT);
        uint2* dst = reinterpret_cast<uint2*>(lds_u);
#pragma unroll
        for (int i = 0; i < 8; ++i) {
            const float4 v = src[tid * 8 + i];
            dst[tid * 8 + i] = make_uint2(pk2(v.x, v.y), pk2(v.z, v.w));
        }
    }
    __syncthreads();

    float acc0[16] = {}, acc1[16] = {}, acc2[16] = {}, acc3[16] = {};

    const f32x4* wrow = reinterpret_cast<const f32x4*>(
        Wu + (size_t)e * ((size_t)DHID * FINT) + (size_t)(wid * 128) * FINT
           + fq * 256 + lane * 4);
    const size_t WSTEP = FINT / 4;  // 256 f32x4 per d-row
    const uint4* xqw = reinterpret_cast<const uint4*>(lds_u) + (size_t)wid * 256;

    f32x4 b0 = LDW(0), b1 = LDW(1), b2 = LDW(2), b3 = LDW(3);
    for (int j = 0; j < 128; j += 4) {
        const bool pf = (j < 124);
        STEP(j + 0, b0) if (pf) b0 = LDW(j + 4);
        STEP(j + 1, b1) if (pf) b1 = LDW(j + 5);
        STEP(j + 2, b2) if (pf) b2 = LDW(j + 6);
        STEP(j + 3, b3) if (pf) b3 = LDW(j + 7);
    }

    // 16 -> 1 tree (x region dead, reuse whole LDS)
    __syncthreads();
    if (wid >= 8) RW(wid - 8)
    __syncthreads();
    if (wid < 8) RR(wid)
    __syncthreads();
    if (wid >= 4 && wid < 8) RW(wid - 4)
    __syncthreads();
    if (wid < 4) RR(wid)
    __syncthreads();
    if (wid >= 2 && wid < 4) RW(wid - 2)
    __syncthreads();
    if (wid < 2) RR(wid)
    __syncthreads();
    if (wid == 1) RW(0)
    __syncthreads();
    if (wid == 0) {
        RR(0)
        float rt[16];
#pragma unroll
        for (int t = 0; t < 16; ++t) rt[t] = route[e * T_TOK + t];
#define ACT(A, t) (rt[t] * fmaxf(A[t], 0.f) * fmaxf(A[t], 0.f))
        uint4* ap = reinterpret_cast<uint4*>(
            a_buf + ((size_t)e * FINT + fq * 256 + lane * 4) * T_TOK);
        uint4 o;
#define ST_COL(A, k0)                                                   \
        o.x = pk2(ACT(A, 0), ACT(A, 1));  o.y = pk2(ACT(A, 2), ACT(A, 3));   \
        o.z = pk2(ACT(A, 4), ACT(A, 5));  o.w = pk2(ACT(A, 6), ACT(A, 7));   \
        ap[k0] = o;                                                          \
        o.x = pk2(ACT(A, 8), ACT(A, 9));  o.y = pk2(ACT(A, 10), ACT(A, 11)); \
        o.z = pk2(ACT(A, 12), ACT(A, 13)); o.w = pk2(ACT(A, 14), ACT(A, 15)); \
        ap[k0 + 1] = o;
        ST_COL(acc0, 0) ST_COL(acc1, 2) ST_COL(acc2, 4) ST_COL(acc3, 6)
#undef ST_COL
#undef ACT
    }
}

// ---------------------------------------------------------------------------
// K3: down-proj. Block=(active e, d-chunk of 512). Waves (wd=wid>>3, wf=wid&7):
// lane owns 4 d at d0 = dc*512 + wd*256 + lane*4; wf owns 128 f-rows.
// a[e] staged bf16 (32 KB); depth-4 prefetch; bf16 tree 8->1 per wd-group.
// ---------------------------------------------------------------------------
__global__ __launch_bounds__(1024, 4) void k_down(
    const ushort_t* __restrict__ a_buf, const float* __restrict__ Wd,
    const int* __restrict__ aidx, const int* __restrict__ nAp,
    float* __restrict__ out_part) {
    const int b = blockIdx.x;
    if (b >= 4 * (*nAp)) return;
    const int e = aidx[b >> 2];
    const int dc = b & 3;
    const int tid = threadIdx.x;
    const int wid = tid >> 6, lane = tid & 63;
    const int wd = wid >> 3, wf = wid & 7;

    __shared__ __align__(16) uint_t lds_u[16384];  // 64 KB (stage uses 32 KB)

    {   // stage a[e] bf16 (32 KB) linearly
        const uint4* src = reinterpret_cast<const uint4*>(a_buf + (size_t)e * FINT * T_TOK);
        uint4* dst = reinterpret_cast<uint4*>(lds_u);
        dst[tid] = src[tid];
        dst[tid + 1024] = src[tid + 1024];
    }
    __syncthreads();

    float acc0[16] = {}, acc1[16] = {}, acc2[16] = {}, acc3[16] = {};

    const int d0 = dc * 512 + wd * 256 + lane * 4;
    const f32x4* wrow = reinterpret_cast<const f32x4*>(
        Wd + (size_t)e * ((size_t)FINT * DHID) + (size_t)(wf * 128) * DHID + d0);
    const size_t WSTEP = DHID / 4;  // 512 f32x4 per f-row
    const uint4* xqw = reinterpret_cast<const uint4*>(lds_u) + (size_t)wf * 256;

    f32x4 b0 = LDW(0), b1 = LDW(1), b2 = LDW(2), b3 = LDW(3);
    for (int j = 0; j < 128; j += 4) {
        const bool pf = (j < 124);
        STEP(j + 0, b0) if (pf) b0 = LDW(j + 4);
        STEP(j + 1, b1) if (pf) b1 = LDW(j + 5);
        STEP(j + 2, b2) if (pf) b2 = LDW(j + 6);
        STEP(j + 3, b3) if (pf) b3 = LDW(j + 7);
    }

    // 8 -> 1 per wd-group (regions wd*4 .. wd*4+3)
    __syncthreads();
    if (wf >= 4) RW(wd * 4 + wf - 4)
    __syncthreads();
    if (wf < 4) RR(wd * 4 + wf)
    __syncthreads();
    if (wf == 2 || wf == 3) RW(wd * 4 + wf - 2)
    __syncthreads();
    if (wf < 2) RR(wd * 4 + wf)
    __syncthreads();
    if (wf == 1) RW(wd * 4)
    __syncthreads();
    if (wf == 0) {
        RR(wd * 4)
        float* op = out_part + (size_t)e * (T_TOK * DHID) + d0;
#pragma unroll
        for (int t = 0; t < 16; ++t)
            *reinterpret_cast<float4*>(op + (size_t)t * DHID) =
                make_float4(acc0[t], acc1[t], acc2[t], acc3[t]);
    }
}

// ---------------------------------------------------------------------------
// K4: out[t][d] = sum over active e of out_part[e][t][d]. Overwrites d_out.
// ---------------------------------------------------------------------------
__global__ void k_comb(const float* __restrict__ out_part, const int* __restrict__ aidx,
                       const int* __restrict__ nAp, float* __restrict__ out) {
    const int i = blockIdx.x * 256 + threadIdx.x;  // [0, T*D/4)
    const int nA = *nAp;
    const size_t off = (size_t)i * 4;
    float4 s = make_float4(0.f, 0.f, 0.f, 0.f);
    for (int a = 0; a < nA; ++a) {
        const float4 v = *reinterpret_cast<const float4*>(
            out_part + (size_t)aidx[a] * (T_TOK * DHID) + off);
        s.x += v.x; s.y += v.y; s.z += v.z; s.w += v.w;
    }
    *reinterpret_cast<float4*>(out + off) = s;
}

// ---------------------------------------------------------------------------
extern "C" void kernel_launch(void* const* d_in, const int* in_sizes, int n_in,
                              void* d_out, int out_size, void* d_ws, size_t ws_size,
                              hipStream_t stream) {
    (void)in_sizes; (void)n_in; (void)out_size; (void)ws_size;
    const float* x   = (const float*)d_in[0];
    const int*   idx = (const int*)d_in[1];
    const float* w   = (const float*)d_in[2];
    const float* Wu  = (const float*)d_in[3];
    const float* Wd  = (const float*)d_in[4];
    float* out = (float*)d_out;

    char* ws = (char*)d_ws;
    float*    route    = (float*)(ws + ROUTE_OFF);
    int*      aidx     = (int*)(ws + AIDX_OFF);
    int*      nA       = (int*)(ws + NA_OFF);
    float*    xT       = (float*)(ws + XT_OFF);
    ushort_t* a_buf    = (ushort_t*)(ws + ABUF_OFF);
    float*    out_part = (float*)(ws + OPART_OFF);

    k_prep<<<DHID / 64, 256, 0, stream>>>(x, idx, w, xT, route, aidx, nA);
    k_up<<<4 * NEXP, 1024, 0, stream>>>(xT, Wu, route, aidx, nA, a_buf);
    k_down<<<4 * NEXP, 1024, 0, stream>>>(a_buf, Wd, aidx, nA, out_part);
    k_comb<<<(T_TOK * DHID / 4) / 256, 256, 0, stream>>>(out_part, aidx, nA, out);
}